// Round 1
// baseline (2653.906 us; speedup 1.0000x reference)
//
#include <hip/hip_runtime.h>

// Conv2d: input (64,8,256,256) f32, filter (8,8,3,3) OIHW, VALID, stride 1.
// out (64,8,254,254) f32.
//
// Block = 256 threads, one (n, 64x16 output tile, all 8 m).
// LDS input buffer holds only 4 channels at a time ([4][18][68] f32, rows
// 272 B = 16B-aligned); channel-halves are pipelined:
//   stage(c0..3) -> sync -> issue-loads(c4..7)->regs ; compute(c0..3)
//   -> sync -> regs->LDS -> sync -> compute(c4..7)
// so the second half's HBM latency hides under the first half's FMAs (T14).
// Filter packed [mg][c][r][m4][s] so each r-step is 3x b128 broadcast reads.
// Thread = 8 consecutive x-pixels x 4 output channels -> 32 accumulators.

#define TW 64
#define TH 16
#define LDS_W 68   // 66 used + 2 junk; 68*4=272 B row stride, 16B-aligned
#define LDS_H 18   // TH + 2
#define NITEM 1224 // 4 ch * 18 rows * 17 vec4 per half

__global__ __launch_bounds__(256, 4)
void conv2d_tile_kernel(const float* __restrict__ inp,
                        const float* __restrict__ filt,
                        float* __restrict__ out) {
    __shared__ __align__(16) float s_f[576];                 // 2304 B
    __shared__ __align__(16) float s_in[4 * LDS_H * LDS_W];  // 19584 B

    const int tid = threadIdx.x;
    const int x0 = blockIdx.x * TW;   // 0,64,128,192
    const int y0 = blockIdx.y * TH;   // 0..240
    const int n  = blockIdx.z;

    const float* in_n = inp + (size_t)n * (8 * 256 * 256);

    // ---- filter stage: repack [m][c][r][s] -> [mg][c][r][m4][s] ----
    for (int idx = tid; idx < 576; idx += 256) {
        int m = idx / 72;
        int c = (idx / 9) % 8;
        int r = (idx % 9) / 3;
        int s = idx % 3;
        s_f[(((m >> 2) * 8 + c) * 3 + r) * 12 + (m & 3) * 3 + s] = filt[idx];
    }

    // ---- stage half 0 (c = 0..3) directly: pure float4 path ----
    #pragma unroll
    for (int i = 0; i < 5; ++i) {
        int idx = tid + i * 256;
        if (idx < NITEM) {
            int c   = idx / 306;          // 0..3
            int rem = idx - c * 306;
            int row = rem / 17;           // 0..17
            int v   = rem - row * 17;     // 0..16
            int iy  = y0 + row;
            int ix  = x0 + 4 * v;
            float4 val = make_float4(0.f, 0.f, 0.f, 0.f);
            // only OOB cases: bottom rows (ty=15) and v==16 sliver at tx=3
            if (iy < 256 && ix + 3 < 256)
                val = *reinterpret_cast<const float4*>(in_n + (c * 256 + iy) * 256 + ix);
            *reinterpret_cast<float4*>(&s_in[(c * LDS_H + row) * LDS_W + 4 * v]) = val;
        }
    }
    __syncthreads();

    const int xg = tid & 7;          // 8 x-groups of 8 pixels
    const int py = (tid >> 3) & 15;  // row within tile
    const int mg = tid >> 7;         // m-half: 0 -> m 0..3, 1 -> m 4..7
    const int px = xg * 8;

    // ---- issue global loads for half 1 (c = 4..7) into registers NOW;
    //      they complete while we compute half 0 ----
    float4 sv[5];
    #pragma unroll
    for (int i = 0; i < 5; ++i) {
        int idx = tid + i * 256;
        sv[i] = make_float4(0.f, 0.f, 0.f, 0.f);
        if (idx < NITEM) {
            int c   = idx / 306;
            int rem = idx - c * 306;
            int row = rem / 17;
            int v   = rem - row * 17;
            int iy  = y0 + row;
            int ix  = x0 + 4 * v;
            if (iy < 256 && ix + 3 < 256)
                sv[i] = *reinterpret_cast<const float4*>(in_n + ((c + 4) * 256 + iy) * 256 + ix);
        }
    }

    float acc[4][8];
    #pragma unroll
    for (int m4 = 0; m4 < 4; ++m4)
        #pragma unroll
        for (int i = 0; i < 8; ++i)
            acc[m4][i] = 0.0f;

    auto compute_half = [&](int h) {
        #pragma unroll
        for (int cc = 0; cc < 4; ++cc) {
            const float* fb = &s_f[((mg * 8 + h * 4 + cc) * 3) * 12];
            const float* ib = &s_in[(cc * LDS_H + py) * LDS_W + px];
            #pragma unroll
            for (int r = 0; r < 3; ++r) {
                // filter: 12 floats, 3x b128 (broadcast: address wave-uniform)
                float4 f0 = *reinterpret_cast<const float4*>(fb + r * 12 + 0);
                float4 f1 = *reinterpret_cast<const float4*>(fb + r * 12 + 4);
                float4 f2 = *reinterpret_cast<const float4*>(fb + r * 12 + 8);
                const float fr[12] = {f0.x, f0.y, f0.z, f0.w,
                                      f1.x, f1.y, f1.z, f1.w,
                                      f2.x, f2.y, f2.z, f2.w};
                // input row: 10 floats, b128+b128+b64 (16B-aligned base)
                const float* ipr = ib + r * LDS_W;
                float4 a0 = *reinterpret_cast<const float4*>(ipr + 0);
                float4 a1 = *reinterpret_cast<const float4*>(ipr + 4);
                float2 a2 = *reinterpret_cast<const float2*>(ipr + 8);
                const float iv[10] = {a0.x, a0.y, a0.z, a0.w,
                                      a1.x, a1.y, a1.z, a1.w,
                                      a2.x, a2.y};
                #pragma unroll
                for (int s = 0; s < 3; ++s)
                    #pragma unroll
                    for (int m4 = 0; m4 < 4; ++m4) {
                        const float fv = fr[m4 * 3 + s];
                        #pragma unroll
                        for (int i2 = 0; i2 < 8; ++i2)
                            acc[m4][i2] = fmaf(iv[i2 + s], fv, acc[m4][i2]);
                    }
            }
        }
    };

    // ---- compute half 0 while half-1 loads are in flight ----
    compute_half(0);

    __syncthreads();   // everyone done READING half-0 slots

    // ---- write half-1 registers into LDS (reuses the same 4 slots) ----
    #pragma unroll
    for (int i = 0; i < 5; ++i) {
        int idx = tid + i * 256;
        if (idx < NITEM) {
            int c   = idx / 306;
            int rem = idx - c * 306;
            int row = rem / 17;
            int v   = rem - row * 17;
            *reinterpret_cast<float4*>(&s_in[(c * LDS_H + row) * LDS_W + 4 * v]) = sv[i];
        }
    }
    __syncthreads();

    // ---- compute half 1 ----
    compute_half(1);

    // ---- store: 4 channels x 8 pixels, float2 (row base is even -> 8B ok) ----
    const int oy  = y0 + py;
    const int ox0 = x0 + px;
    if (oy < 254) {
        #pragma unroll
        for (int m4 = 0; m4 < 4; ++m4) {
            float* op = out + ((((size_t)n * 8 + mg * 4 + m4) * 254 + oy) * 254 + ox0);
            if (ox0 + 8 <= 254) {
                #pragma unroll
                for (int i = 0; i < 8; i += 2)
                    *reinterpret_cast<float2*>(op + i) =
                        make_float2(acc[m4][i], acc[m4][i + 1]);
            } else {
                #pragma unroll
                for (int i = 0; i < 8; ++i)
                    if (ox0 + i < 254) op[i] = acc[m4][i];
            }
        }
    }
}

extern "C" void kernel_launch(void* const* d_in, const int* in_sizes, int n_in,
                              void* d_out, int out_size, void* d_ws, size_t ws_size,
                              hipStream_t stream) {
    const float* inp  = (const float*)d_in[0];   // (64,8,256,256)
    const float* filt = (const float*)d_in[1];   // (8,8,3,3)
    float* outp = (float*)d_out;                 // (64,8,254,254)

    dim3 grid(4, 16, 64);
    dim3 block(256);
    conv2d_tile_kernel<<<grid, block, 0, stream>>>(inp, filt, outp);
}

// Round 2
// 303.303 us; speedup vs baseline: 8.7500x; 8.7500x over previous
//
#include <hip/hip_runtime.h>

// Conv2d via implicit-GEMM MFMA: input (64,8,256,256) f32, filter (8,8,3,3)
// OIHW, VALID, stride 1 -> out (64,8,254,254) f32.
//
// mfma_f32_16x16x32_f16: M = output channel m (8 valid of 16),
// N = 16 consecutive x pixels (fixed y), K = 96 = 3 chunks of 32.
// Semantic k-slot: chunk kk, lane-group g=(lane>>4), elem j:
//   q = kk*4+g (q = r*3+s, valid q<=8), c = j.
// A (filter) zeroed for q>8 or m>=8; B address uses q clamped to 8 (the
// product is zero there, data is don't-care). A and B use the same hardware
// slot mapping, so only slot agreement matters, not the k bijection.
//
// LDS: channel-last f16 tile s_in[18 rows][66 x][8 c] -> every B-fragment is
// ONE aligned ds_read_b128; 16-lane groups read 256 B contiguous => no bank
// conflicts. Block = 256 thr = 4 waves; block tile = 16 y x 64 x, all 8 m.
// Wave w handles y rows w*4..w*4+3, 4 x-groups of 16. 3 MFMA per 16x16 tile.

#define XW 66
#define ROWS 18

typedef _Float16 half8 __attribute__((ext_vector_type(8)));
typedef float floatx4 __attribute__((ext_vector_type(4)));

__global__ __launch_bounds__(256, 4)
void conv2d_mfma_kernel(const float* __restrict__ inp,
                        const float* __restrict__ filt,
                        float* __restrict__ out) {
    __shared__ __align__(16) _Float16 s_in[ROWS * XW * 8];  // 19008 B

    const int tid = threadIdx.x;
    const int x0 = blockIdx.x * 64;   // 0,64,128,192
    const int y0 = blockIdx.y * 16;   // 0..240
    const int n  = blockIdx.z;

    const float* in_n = inp + (size_t)n * (8 * 256 * 256);

    // ---- stage input tile: 18 rows x 66 x, 8 channels channel-last, f32->f16
    #pragma unroll
    for (int it = 0; it < 5; ++it) {
        int cell = tid + it * 256;            // (row, col) over 18*66 = 1188
        if (cell < ROWS * XW) {
            int row = cell / XW;
            int col = cell - row * XW;
            int iy = y0 + row;
            int ix = x0 + col;
            bool ok = (iy < 256) && (ix < 256);
            const float* p = in_n + (iy * 256 + ix);
            half8 h;
            #pragma unroll
            for (int c = 0; c < 8; ++c) {
                float v = ok ? p[c * 65536] : 0.0f;   // 256*256 plane stride
                h[c] = (_Float16)v;
            }
            *reinterpret_cast<half8*>(&s_in[cell * 8]) = h;
        }
    }

    // ---- A-fragments (filter), built once; filter is 2.3 KB and L2-hot ----
    const int lane = tid & 63;
    const int w    = tid >> 6;     // wave 0..3
    const int lx   = lane & 15;    // A: row m ; B: col pixel ; D: col pixel
    const int g    = lane >> 4;    // k-slot group

    half8 afrag[3];
    int   dcell[3];                // B-fragment cell offset (r*XW + s) per chunk
    #pragma unroll
    for (int kk = 0; kk < 3; ++kk) {
        int q  = kk * 4 + g;               // 0..11
        int qa = q > 8 ? 8 : q;            // clamp for address only
        int r  = qa / 3;
        int s  = qa - r * 3;
        dcell[kk] = r * XW + s;
        half8 a = {};                      // zeros: q>8 slots, m>=8 rows
        if (q <= 8 && lx < 8) {
            #pragma unroll
            for (int j = 0; j < 8; ++j)    // filt[m][c][r][s] = m*72 + c*9 + q
                a[j] = (_Float16)filt[lx * 72 + j * 9 + q];
        }
        afrag[kk] = a;
    }

    __syncthreads();

    // ---- compute: per wave 4 y-rows x 4 x-groups, 3 chained MFMA each ----
    #pragma unroll
    for (int yy = 0; yy < 4; ++yy) {
        const int y = w * 4 + yy;                  // local y row 0..15
        const int rowbase = y * XW + lx;           // cell of this lane's pixel
        #pragma unroll
        for (int xg = 0; xg < 4; ++xg) {
            floatx4 acc = {0.0f, 0.0f, 0.0f, 0.0f};
            #pragma unroll
            for (int kk = 0; kk < 3; ++kk) {
                const half8 b = *reinterpret_cast<const half8*>(
                    &s_in[(rowbase + xg * 16 + dcell[kk]) * 8]);
                acc = __builtin_amdgcn_mfma_f32_16x16x32_f16(
                          afrag[kk], b, acc, 0, 0, 0);
            }
            // D layout: col = lane&15 (pixel), row = g*4 + i (m; valid g<2)
            const int ox = x0 + xg * 16 + lx;
            const int oy = y0 + y;
            if (g < 2 && oy < 254 && ox < 254) {
                #pragma unroll
                for (int i = 0; i < 4; ++i) {
                    const int m = g * 4 + i;
                    out[(((size_t)n * 8 + m) * 254 + oy) * 254 + ox] = acc[i];
                }
            }
        }
    }
}

extern "C" void kernel_launch(void* const* d_in, const int* in_sizes, int n_in,
                              void* d_out, int out_size, void* d_ws, size_t ws_size,
                              hipStream_t stream) {
    const float* inp  = (const float*)d_in[0];   // (64,8,256,256)
    const float* filt = (const float*)d_in[1];   // (8,8,3,3)
    float* outp = (float*)d_out;                 // (64,8,254,254)

    dim3 grid(4, 16, 64);
    dim3 block(256);
    conv2d_mfma_kernel<<<grid, block, 0, stream>>>(inp, filt, outp);
}